// Round 1
// 63.620 us; speedup vs baseline: 1.0767x; 1.0767x over previous
//
#include <hip/hip_runtime.h>

#define WAVE 64
#define NWORDS 320   // ceil(10000/32)=313 words, padded to 5*64 for clean clearing

__device__ __forceinline__ int rf(int x) { return __builtin_amdgcn_readfirstlane(x); }
__device__ __forceinline__ float bperm_f(int addr, float v) {
    return __int_as_float(__builtin_amdgcn_ds_bpermute(addr, __float_as_int(v)));
}
__device__ __forceinline__ int bperm_i(int addr, int v) {
    return __builtin_amdgcn_ds_bpermute(addr, v);
}

// One wave per pair.
// Fast path (c == 1.0):
//   Screen: per-wave EXACT token-id bitset in LDS (V=10000 -> 313 words).
//   Insert pattern prefix tokens (1 ds_or), probe text prefix tokens
//   (1 ds_read), ONE ballot -> colmask (bit j = any pattern match in col j).
//   This replaces the previous O(n) readlane+ballot screening loop; the
//   per-CU-shared SALU chain (s_lshl/s_or per column) disappears.
//   colmask==0 (~91% of pairs) -> dist = max(la,lb).
//   Survivors: run-skipping Myers (unchanged, previously validated) — runs of
//   empty columns while Mv==0 collapse to Pv <<= z; Eq=0 steps while Mv!=0
//   use the reduced 3-op update; only match columns (mean ~1.3) pay the full
//   step. End-only score: n + pcnt(Pv&lowmask(m)) - pcnt(Mv&lowmask(m)).
// Fallback (general c): anti-diagonal float DP (validated absmax=0).
__global__ __launch_bounds__(256) void edit_distance_kernel(
    const int* __restrict__ t1, const int* __restrict__ t2,
    const int* __restrict__ len1, const int* __restrict__ len2,
    const float* __restrict__ subc, float* __restrict__ out, int B)
{
    __shared__ unsigned int bset[4][NWORDS];   // 5 KiB/block, per-wave private

    const int tid  = blockIdx.x * blockDim.x + threadIdx.x;
    const int pair = tid >> 6;
    const int lane = tid & (WAVE - 1);
    if (pair >= B) return;
    unsigned int* bs = bset[threadIdx.x >> 6];

    const float c      = subc[0];
    const int   a_tok  = t1[pair * 64 + lane];
    const int   b_tok  = t2[pair * 64 + lane];
    const int   la     = rf(len1[pair]);
    const int   lb     = rf(len2[pair]);
    const bool  unit_c = (rf(__float_as_int(c)) == __float_as_int(1.0f));

    if (unit_c) {
        const bool sw  = lb > la;
        const int  m   = sw ? lb : la;        // pattern length = max(la,lb)
        const int  n   = sw ? la : lb;        // text length    = min(la,lb)
        const int  pat = sw ? b_tok : a_tok;  // lane i holds pattern[i]
        const int  txt = sw ? a_tok : b_tok;  // lane j holds text[j]
        // Rows >= m must never match (tokens are >= 0, so -2 is safe).
        const int  pat_m = (lane < m) ? pat : -2;

        // ---- O(1) screen: exact per-wave token bitset ----
        {
            unsigned long long* bs64 = (unsigned long long*)bs;
            bs64[lane]      = 0ull;          // words   0..127
            bs64[lane + 64] = 0ull;          // words 128..255
            bs[lane + 256]  = 0u;            // words 256..319
        }
        if (lane < m) atomicOr(&bs[((unsigned)pat) >> 5], 1u << (pat & 31));
        unsigned int hit = 0u;
        if (lane < n) hit = (bs[((unsigned)txt) >> 5] >> (txt & 31)) & 1u;
        const unsigned long long colmask = __ballot(hit != 0u);

        if (colmask == 0ull) {                // no match in prefixes (or n==0)
            if (lane == 0) out[pair] = (float)m;
            return;
        }

        // ---- Run-skipping Myers over match columns ----
        unsigned long long Pv = ~0ull, Mv = 0ull;
        unsigned long long cols = colmask;
        int jcur = 0;
        while (cols) {
            const int jn = __builtin_ctzll(cols);
            cols &= cols - 1;
            // columns jcur..jn-1 have Eq == 0
            while (jcur < jn && Mv != 0ull) {   // reduced Eq=0 step
                unsigned long long Ph = ((Mv | ~Pv) << 1) | 1ull;
                const unsigned long long Pv2 = ~(Mv | Ph);
                Mv = Ph & Mv;
                Pv = Pv2;
                ++jcur;
            }
            if (jcur < jn) { Pv <<= (jn - jcur); jcur = jn; }  // Mv==0 run skip
            // full step at match column jn
            const int bj = __builtin_amdgcn_readlane(txt, jn);
            const unsigned long long Eq = __ballot(pat_m == bj);
            const unsigned long long Xv = Eq | Mv;
            const unsigned long long Xh = (((Eq & Pv) + Pv) ^ Pv) | Eq;
            unsigned long long Ph = Mv | ~(Xh | Pv);
            const unsigned long long Mh = Pv & Xh;
            Ph = (Ph << 1) | 1ull;
            Pv = (Mh << 1) | ~(Xv | Ph);
            Mv = Ph & Xv;
            jcur = jn + 1;
        }
        // tail columns jcur..n-1 (all Eq == 0)
        while (Mv != 0ull && jcur < n) {
            unsigned long long Ph = ((Mv | ~Pv) << 1) | 1ull;
            const unsigned long long Pv2 = ~(Mv | Ph);
            Mv = Ph & Mv;
            Pv = Pv2;
            ++jcur;
        }
        Pv <<= (n - jcur);                     // Mv==0 here

        const unsigned long long mask = ~0ull >> (64 - m);   // m>=1 (colmask!=0)
        const int score = n + __popcll(Pv & mask) - __popcll(Mv & mask);
        if (lane == 0) out[pair] = (float)score;
    } else {
        // ---------- general-cost anti-diagonal DP ----------
        const int rotaddr = ((lane + 63) & 63) << 2;
        int bcur = bperm_i(((64 - lane) & 63) << 2, b_tok);
        const int  tmax   = rf(la + lb - 1);
        const bool lane0  = (lane == 0);
        const int  target = lb + lane - 1;

        float cur   = (float)(lane + 1);
        float diagn = 0.f;
        float saved = 0.f;
        float ft    = 0.f;

        for (int t = 0; t < tmax; ++t) {
            float up   = bperm_f(rotaddr, cur);
            float diag = diagn;
            if (lane0) { up = ft + 1.f; diag = ft; }

            const float cost = (a_tok == bcur) ? 0.f : c;
            const float v = fminf(fminf(up, cur) + 1.f, diag + cost);

            if (t >= lane) {
                cur = v;
                if (t == target) saved = v;
            }
            diagn = up;
            bcur  = bperm_i(rotaddr, bcur);
            ft   += 1.f;
        }

        int src = (la > 0) ? (la - 1) : 0;
        float ans = __shfl(saved, src, WAVE);
        if (la == 0)      ans = (float)lb;
        else if (lb == 0) ans = (float)la;

        if (lane == 0) out[pair] = ans;
    }
}

extern "C" void kernel_launch(void* const* d_in, const int* in_sizes, int n_in,
                              void* d_out, int out_size, void* d_ws, size_t ws_size,
                              hipStream_t stream) {
    const int*   tokens1 = (const int*)d_in[0];
    const int*   tokens2 = (const int*)d_in[1];
    const int*   len1    = (const int*)d_in[2];
    const int*   len2    = (const int*)d_in[3];
    const float* subc    = (const float*)d_in[4];
    float*       out     = (float*)d_out;

    const int B = in_sizes[2];           // 8192
    const int threads = 256;             // 4 waves (pairs) per block
    const int blocks  = (B * WAVE + threads - 1) / threads;
    edit_distance_kernel<<<blocks, threads, 0, stream>>>(
        tokens1, tokens2, len1, len2, subc, out, B);
}

// Round 2
// 63.466 us; speedup vs baseline: 1.0793x; 1.0024x over previous
//
#include <hip/hip_runtime.h>

#define WAVE 64
#define NWORDS 256   // 8192-bit lossy-superset hash bitset (tok & 8191)

__device__ __forceinline__ int rf(int x) { return __builtin_amdgcn_readfirstlane(x); }
__device__ __forceinline__ float bperm_f(int addr, float v) {
    return __int_as_float(__builtin_amdgcn_ds_bpermute(addr, __float_as_int(v)));
}
__device__ __forceinline__ int bperm_i(int addr, int v) {
    return __builtin_amdgcn_ds_bpermute(addr, v);
}

// One wave per pair.
// Fast path (c == 1.0):
//   Screen: per-wave 8192-bit hash bitset in LDS (h = tok & 8191). This is a
//   SUPERSET filter: colmask bit j set iff column j MAY contain a match.
//   - clear = ONE ds_write_b128 per lane (1024 B exactly)
//   - insert pattern prefix (1 ds_or), probe text prefix (1 ds_read),
//     ONE ballot -> colmask.
//   colmask==0 (~89% of pairs) -> no true matches possible -> dist = max(la,lb).
//   Survivors: run-skipping Myers. Run-skips only touch columns NOT in
//   colmask (truly Eq==0 since colmask is a superset); full steps compute the
//   EXACT Eq via ballot, and the full-step update is valid for Eq==0, so
//   false-positive columns cost time but never correctness.
//   End-only score: n + pcnt(Pv&lowmask(m)) - pcnt(Mv&lowmask(m)).
// Fallback (general c): anti-diagonal float DP (validated absmax=0).
__global__ __launch_bounds__(256) void edit_distance_kernel(
    const int* __restrict__ t1, const int* __restrict__ t2,
    const int* __restrict__ len1, const int* __restrict__ len2,
    const float* __restrict__ subc, float* __restrict__ out, int B)
{
    __shared__ __align__(16) unsigned int bset[4][NWORDS];   // 4 KiB/block

    const int tid  = blockIdx.x * blockDim.x + threadIdx.x;
    const int pair = tid >> 6;
    const int lane = tid & (WAVE - 1);
    if (pair >= B) return;
    unsigned int* bs = bset[threadIdx.x >> 6];

    // Wave-uniform scalar loads (s_load through constant cache).
    const int   wv = rf(pair);
    const int   la = len1[wv];
    const int   lb = len2[wv];
    const float c  = subc[0];
    const bool  unit_c = (__float_as_int(c) == 0x3f800000);

    // Per-lane token loads (coalesced, 256 B per wave per array).
    const int a_tok = t1[pair * 64 + lane];
    const int b_tok = t2[pair * 64 + lane];

    if (unit_c) {
        const bool sw  = lb > la;
        const int  m   = sw ? lb : la;        // pattern length = max(la,lb)
        const int  n   = sw ? la : lb;        // text length    = min(la,lb)
        const int  pat = sw ? b_tok : a_tok;  // lane i holds pattern[i]
        const int  txt = sw ? a_tok : b_tok;  // lane j holds text[j]
        // Rows >= m must never match (tokens are >= 0, so -2 is safe).
        const int  pat_m = (lane < m) ? pat : -2;

        // ---- O(1) superset screen: hashed per-wave token bitset ----
        {
            uint4 z; z.x = 0u; z.y = 0u; z.z = 0u; z.w = 0u;
            ((uint4*)bs)[lane] = z;          // one ds_write_b128: words 0..255
        }
        if (lane < m) atomicOr(&bs[(((unsigned)pat) >> 5) & (NWORDS - 1)],
                               1u << (pat & 31));
        unsigned int hit = 0u;
        if (lane < n) hit = (bs[(((unsigned)txt) >> 5) & (NWORDS - 1)]
                             >> (txt & 31)) & 1u;
        const unsigned long long colmask = __ballot(hit != 0u);

        if (colmask == 0ull) {                // no match in prefixes (or n==0)
            if (lane == 0) out[pair] = (float)m;
            return;
        }

        // ---- Run-skipping Myers over (superset of) match columns ----
        unsigned long long Pv = ~0ull, Mv = 0ull;
        unsigned long long cols = colmask;
        int jcur = 0;
        while (cols) {
            const int jn = __builtin_ctzll(cols);
            cols &= cols - 1;
            // columns jcur..jn-1 have Eq == 0 (superset guarantee)
            while (jcur < jn && Mv != 0ull) {   // reduced Eq=0 step
                unsigned long long Ph = ((Mv | ~Pv) << 1) | 1ull;
                const unsigned long long Pv2 = ~(Mv | Ph);
                Mv = Ph & Mv;
                Pv = Pv2;
                ++jcur;
            }
            if (jcur < jn) { Pv <<= (jn - jcur); jcur = jn; }  // Mv==0 run skip
            // full step at candidate column jn (Eq computed EXACTLY)
            const int bj = __builtin_amdgcn_readlane(txt, jn);
            const unsigned long long Eq = __ballot(pat_m == bj);
            const unsigned long long Xv = Eq | Mv;
            const unsigned long long Xh = (((Eq & Pv) + Pv) ^ Pv) | Eq;
            unsigned long long Ph = Mv | ~(Xh | Pv);
            const unsigned long long Mh = Pv & Xh;
            Ph = (Ph << 1) | 1ull;
            Pv = (Mh << 1) | ~(Xv | Ph);
            Mv = Ph & Xv;
            jcur = jn + 1;
        }
        // tail columns jcur..n-1 (all Eq == 0)
        while (Mv != 0ull && jcur < n) {
            unsigned long long Ph = ((Mv | ~Pv) << 1) | 1ull;
            const unsigned long long Pv2 = ~(Mv | Ph);
            Mv = Ph & Mv;
            Pv = Pv2;
            ++jcur;
        }
        Pv <<= (n - jcur);                     // Mv==0 here

        const unsigned long long mask = ~0ull >> (64 - m);   // m>=1 (colmask!=0)
        const int score = n + __popcll(Pv & mask) - __popcll(Mv & mask);
        if (lane == 0) out[pair] = (float)score;
    } else {
        // ---------- general-cost anti-diagonal DP ----------
        const int rotaddr = ((lane + 63) & 63) << 2;
        int bcur = bperm_i(((64 - lane) & 63) << 2, b_tok);
        const int  tmax   = la + lb - 1;       // scalar (la, lb uniform)
        const bool lane0  = (lane == 0);
        const int  target = lb + lane - 1;

        float cur   = (float)(lane + 1);
        float diagn = 0.f;
        float saved = 0.f;
        float ft    = 0.f;

        for (int t = 0; t < tmax; ++t) {
            float up   = bperm_f(rotaddr, cur);
            float diag = diagn;
            if (lane0) { up = ft + 1.f; diag = ft; }

            const float cost = (a_tok == bcur) ? 0.f : c;
            const float v = fminf(fminf(up, cur) + 1.f, diag + cost);

            if (t >= lane) {
                cur = v;
                if (t == target) saved = v;
            }
            diagn = up;
            bcur  = bperm_i(rotaddr, bcur);
            ft   += 1.f;
        }

        int src = (la > 0) ? (la - 1) : 0;
        float ans = __shfl(saved, src, WAVE);
        if (la == 0)      ans = (float)lb;
        else if (lb == 0) ans = (float)la;

        if (lane == 0) out[pair] = ans;
    }
}

extern "C" void kernel_launch(void* const* d_in, const int* in_sizes, int n_in,
                              void* d_out, int out_size, void* d_ws, size_t ws_size,
                              hipStream_t stream) {
    const int*   tokens1 = (const int*)d_in[0];
    const int*   tokens2 = (const int*)d_in[1];
    const int*   len1    = (const int*)d_in[2];
    const int*   len2    = (const int*)d_in[3];
    const float* subc    = (const float*)d_in[4];
    float*       out     = (float*)d_out;

    const int B = in_sizes[2];           // 8192
    const int threads = 256;             // 4 waves (pairs) per block
    const int blocks  = (B * WAVE + threads - 1) / threads;
    edit_distance_kernel<<<blocks, threads, 0, stream>>>(
        tokens1, tokens2, len1, len2, subc, out, B);
}